// Round 1
// baseline (161.020 us; speedup 1.0000x reference)
//
#include <hip/hip_runtime.h>

#define D 128

// Kernel 1: find segment boundaries in sorted seg_ids -> seg_start[B+1]
__global__ void seg_bounds_kernel(const int* __restrict__ seg_ids,
                                  int* __restrict__ seg_start,
                                  int T, int B) {
    int t = blockIdx.x * blockDim.x + threadIdx.x;
    if (t >= T) return;
    if (t == 0) {
        seg_start[0] = 0;
    } else if (seg_ids[t] != seg_ids[t - 1]) {
        seg_start[seg_ids[t]] = t;
    }
    if (t == T - 1) seg_start[B] = T;
}

// Kernel 2: one block per segment. 4 waves; each wave handles one candidate
// per iteration (64 lanes x float2 = 512B row), butterfly-reduce the dot,
// online softmax in base-2 domain, then combine waves via LDS.
__global__ __launch_bounds__(256) void seg_logsoftmax_kernel(
    const float* __restrict__ graph_embed,
    const float* __restrict__ tpl_embedding,
    const int* __restrict__ cand_idx,
    const int* __restrict__ target_pos,
    const int* __restrict__ seg_start,
    float* __restrict__ out)
{
    const int b     = blockIdx.x;
    const int lane  = threadIdx.x & 63;
    const int wave  = threadIdx.x >> 6;
    const int nwave = blockDim.x >> 6;

    const int start = seg_start[b];
    const int end   = seg_start[b + 1];
    const int tp    = target_pos[b];

    // graph embedding fragment for this lane (same for all 4 waves; L1-cached)
    const float2 gv = ((const float2*)(graph_embed + (size_t)b * D))[lane];

    const float LOG2E = 1.4426950408889634f;

    float m   = -INFINITY;  // running max (base-2 scaled logits)
    float s   = 0.0f;       // running sum of 2^(x - m)
    float tgt = -INFINITY;  // target logit (base-2 scaled)

    for (int t = start + wave; t < end; t += nwave) {
        const int c = cand_idx[t];
        const float2 xv = ((const float2*)(tpl_embedding + (size_t)c * D))[lane];
        float p = fmaf(gv.x, xv.x, gv.y * xv.y);
        #pragma unroll
        for (int off = 32; off >= 1; off >>= 1)
            p += __shfl_xor(p, off);
        const float x2 = p * LOG2E;
        if (t == tp) tgt = x2;
        // wave-uniform branch: max update is rare (~ln(n) times per segment)
        if (x2 <= m) {
            s += exp2f(x2 - m);
        } else {
            s = fmaf(s, exp2f(m - x2), 1.0f);
            m = x2;
        }
    }

    __shared__ float sm[8], ss[8], st[8];
    if (lane == 0) { sm[wave] = m; ss[wave] = s; st[wave] = tgt; }
    __syncthreads();

    if (threadIdx.x == 0) {
        float M = -INFINITY;
        for (int w = 0; w < nwave; ++w) M = fmaxf(M, sm[w]);
        float S = 0.0f, Tg = -INFINITY;
        for (int w = 0; w < nwave; ++w) {
            if (ss[w] > 0.0f) S += ss[w] * exp2f(sm[w] - M);
            Tg = fmaxf(Tg, st[w]);
        }
        // back to natural log: ln(x) = log2(x) * ln(2)
        out[b] = (Tg - M - log2f(S)) * 0.69314718055994531f;
    }
}

extern "C" void kernel_launch(void* const* d_in, const int* in_sizes, int n_in,
                              void* d_out, int out_size, void* d_ws, size_t ws_size,
                              hipStream_t stream) {
    const float* graph_embed   = (const float*)d_in[0];
    const float* tpl_embedding = (const float*)d_in[1];
    const int*   cand_idx      = (const int*)d_in[2];
    const int*   seg_ids       = (const int*)d_in[3];
    const int*   target_pos    = (const int*)d_in[4];
    float*       out           = (float*)d_out;

    const int B = in_sizes[0] / D;   // 8192
    const int T = in_sizes[2];       // 524288

    int* seg_start = (int*)d_ws;     // (B+1) ints, rebuilt every launch

    seg_bounds_kernel<<<(T + 255) / 256, 256, 0, stream>>>(seg_ids, seg_start, T, B);
    seg_logsoftmax_kernel<<<B, 256, 0, stream>>>(graph_embed, tpl_embedding,
                                                 cand_idx, target_pos, seg_start, out);
}

// Round 2
// 134.924 us; speedup vs baseline: 1.1934x; 1.1934x over previous
//
#include <hip/hip_runtime.h>

#define D 128
#define LOG2E 1.4426950408889634f
#define LN2   0.6931471805599453f

// Kernel 1: find segment boundaries in sorted seg_ids -> seg_start[B+1]
__global__ void seg_bounds_kernel(const int* __restrict__ seg_ids,
                                  int* __restrict__ seg_start,
                                  int T, int B) {
    int t = blockIdx.x * blockDim.x + threadIdx.x;
    if (t >= T) return;
    if (t == 0) {
        seg_start[0] = 0;
    } else if (seg_ids[t] != seg_ids[t - 1]) {
        seg_start[seg_ids[t]] = t;
    }
    if (t == T - 1) seg_start[B] = T;
}

// Phase A: logits[t] = dot(graph_embed[seg_ids[t]], tpl_embedding[cand_idx[t]]).
// Half-wave (32 lanes x float4 = 512B row) per candidate; grid-stride with
// 2-way unroll -> >=4 row loads in flight per wave, no serial chains.
__global__ __launch_bounds__(256) void logits_kernel(
    const float* __restrict__ graph_embed,
    const float* __restrict__ tpl_embedding,
    const int* __restrict__ cand_idx,
    const int* __restrict__ seg_ids,
    float* __restrict__ logits,
    int T)
{
    const int sl  = threadIdx.x & 31;                              // lane in half-wave
    const int hw  = (blockIdx.x * blockDim.x + threadIdx.x) >> 5;  // half-wave id
    const int nhw = (gridDim.x * blockDim.x) >> 5;

    for (int t0 = hw; t0 < T; t0 += 2 * nhw) {
        const int t1 = t0 + nhw;
        const bool has1 = (t1 < T);

        const int c0 = cand_idx[t0];
        const int s0 = seg_ids[t0];
        const int c1 = has1 ? cand_idx[t1] : c0;
        const int s1 = has1 ? seg_ids[t1] : s0;

        const float4 x0 = ((const float4*)(tpl_embedding + (size_t)c0 * D))[sl];
        const float4 g0 = ((const float4*)(graph_embed   + (size_t)s0 * D))[sl];
        const float4 x1 = ((const float4*)(tpl_embedding + (size_t)c1 * D))[sl];
        const float4 g1 = ((const float4*)(graph_embed   + (size_t)s1 * D))[sl];

        float p0 = fmaf(g0.x, x0.x, fmaf(g0.y, x0.y, fmaf(g0.z, x0.z, g0.w * x0.w)));
        float p1 = fmaf(g1.x, x1.x, fmaf(g1.y, x1.y, fmaf(g1.z, x1.z, g1.w * x1.w)));

        #pragma unroll
        for (int off = 16; off >= 1; off >>= 1) {
            p0 += __shfl_xor(p0, off);
            p1 += __shfl_xor(p1, off);
        }
        if (sl == 0) {
            logits[t0] = p0;
            if (has1) logits[t1] = p1;
        }
    }
}

// Phase B: one wave per segment. Lane-per-candidate online softmax (64
// independent (m,s) chains), butterfly merge, target read directly.
__global__ __launch_bounds__(64) void seg_reduce_kernel(
    const float* __restrict__ logits,
    const int* __restrict__ seg_start,
    const int* __restrict__ target_pos,
    float* __restrict__ out)
{
    const int b    = blockIdx.x;
    const int lane = threadIdx.x;
    const int start = seg_start[b];
    const int end   = seg_start[b + 1];

    float m = -3.0e38f;  // running max (base-2 domain); finite sentinel avoids inf-inf
    float s = 0.0f;

    for (int t = start + lane; t < end; t += 64) {
        const float x = logits[t] * LOG2E;
        if (x <= m) {
            s += exp2f(x - m);
        } else {
            s = fmaf(s, exp2f(m - x), 1.0f);
            m = x;
        }
    }

    #pragma unroll
    for (int off = 32; off >= 1; off >>= 1) {
        const float m2 = __shfl_xor(m, off);
        const float s2 = __shfl_xor(s, off);
        const float M  = fmaxf(m, m2);
        s = s * exp2f(m - M) + s2 * exp2f(m2 - M);
        m = M;
    }

    if (lane == 0) {
        const float tl = logits[target_pos[b]] * LOG2E;
        out[b] = (tl - m - log2f(s)) * LN2;
    }
}

extern "C" void kernel_launch(void* const* d_in, const int* in_sizes, int n_in,
                              void* d_out, int out_size, void* d_ws, size_t ws_size,
                              hipStream_t stream) {
    const float* graph_embed   = (const float*)d_in[0];
    const float* tpl_embedding = (const float*)d_in[1];
    const int*   cand_idx      = (const int*)d_in[2];
    const int*   seg_ids       = (const int*)d_in[3];
    const int*   target_pos    = (const int*)d_in[4];
    float*       out           = (float*)d_out;

    const int B = in_sizes[0] / D;   // 8192
    const int T = in_sizes[2];       // 524288

    // ws layout: seg_start[B+1] ints, then logits[T] floats (256B aligned)
    int*   seg_start = (int*)d_ws;
    float* logits    = (float*)d_ws + (((B + 1) + 63) & ~63);

    seg_bounds_kernel<<<(T + 255) / 256, 256, 0, stream>>>(seg_ids, seg_start, T, B);

    // 2048 blocks x 256 = 524288 threads (full residency); each half-wave
    // handles ~32 candidates via the 2-way unrolled grid-stride loop.
    logits_kernel<<<2048, 256, 0, stream>>>(graph_embed, tpl_embedding,
                                            cand_idx, seg_ids, logits, T);

    seg_reduce_kernel<<<B, 64, 0, stream>>>(logits, seg_start, target_pos, out);
}